// Round 11
// baseline (1452.925 us; speedup 1.0000x reference)
//
#include <hip/hip_runtime.h>

// ============================================================================
// VQ-VAE forward, fp32, NCHW — numpy-fp32 bit-replication (PASSED R10).
//   FROZEN (bit-exact vs ref=np, do not reorder arithmetic):
//     - encoder convs: sequential __fmaf_rn in (ci,kh,kw) order
//     - zz/ee: numpy pairwise-8 reduction; d = (zz+ee) - 2*dot, strict-<
//   DECODER (loose tolerance): restructured for speed.
//   R11: deconv_s2 -> deconv_s2_v2 (4co x 8ow register blocking, vector LDS,
//        fewer chunks/barriers). Same per-output product grouping => recon
//        bits unchanged.
// d_out layout (floats): [x_recon 128*3*131*131][vq_loss][idx 32768]
// ============================================================================

// numpy pairwise reduction for n=64 contiguous squares
template<typename F>
__device__ __forceinline__ float pairwise64_sq(F get)
{
    float r[8];
    #pragma unroll
    for (int j = 0; j < 8; ++j) {
        const float v = get(j);
        r[j] = __fmul_rn(v, v);
    }
    #pragma unroll
    for (int b = 1; b < 8; ++b)
        #pragma unroll
        for (int j = 0; j < 8; ++j) {
            const float v = get(8 * b + j);
            r[j] = __fadd_rn(r[j], __fmul_rn(v, v));
        }
    return __fadd_rn(__fadd_rn(__fadd_rn(r[0], r[1]), __fadd_rn(r[2], r[3])),
                     __fadd_rn(__fadd_rn(r[4], r[5]), __fadd_rn(r[6], r[7])));
}

// ---------------- encoder conv (FROZEN arithmetic) ----------------
template<int CIN, int COUT, int HIN, int TOH, int ICC, bool RELU>
__global__ void __launch_bounds__(256)
conv_s2(const float* __restrict__ x, const float* __restrict__ w,
        const float* __restrict__ bias, float* __restrict__ y)
{
    constexpr int WIN = HIN, HOUT = HIN / 2, WOUT = WIN / 2;
    constexpr int NOWG = WOUT / 4, NOCG = COUT / 4;
    static_assert(TOH * NOWG * NOCG == 256, "block mismatch");
    static_assert(CIN % ICC == 0, "chunking mismatch");
    constexpr int NCH = CIN / ICC;
    constexpr int NIR = 2 * TOH + 2;
    constexpr int LW  = WIN + 2;
    constexpr int SWP = ICC * 16 + 1;

    __shared__ float sx[ICC][NIR][LW];
    __shared__ float sw[COUT][SWP];

    const int n   = blockIdx.x;
    const int oh0 = blockIdx.y * TOH;
    const int t   = threadIdx.x;
    const int owg = t % NOWG;
    const int ohl = (t / NOWG) % TOH;
    const int ocg = t / (NOWG * TOH);
    const int oh  = oh0 + ohl;
    const int ow0 = owg * 4;
    const int ih0 = 2 * oh0 - 1;

    float acc[4][4];
    #pragma unroll
    for (int i = 0; i < 4; ++i)
        #pragma unroll
        for (int j = 0; j < 4; ++j) acc[i][j] = 0.f;

    for (int ch = 0; ch < NCH; ++ch) {
        const int ic0 = ch * ICC;
        for (int idx = t; idx < COUT * ICC * 16; idx += 256) {
            const int k   = idx & 15;
            const int icl = (idx >> 4) % ICC;
            const int oc  = idx / (16 * ICC);
            sw[oc][icl * 16 + k] = w[(oc * CIN + ic0 + icl) * 16 + k];
        }
        for (int idx = t; idx < ICC * NIR * LW; idx += 256) {
            const int c   = idx % LW;
            const int r   = (idx / LW) % NIR;
            const int icl = idx / (LW * NIR);
            const int ih  = ih0 + r;
            const int iw  = c - 1;
            float v = 0.f;
            if (ih >= 0 && ih < HIN && iw >= 0 && iw < WIN)
                v = x[((size_t)(n * CIN + ic0 + icl) * HIN + ih) * WIN + iw];
            sx[icl][r][c] = v;
        }
        __syncthreads();
        #pragma unroll
        for (int icl = 0; icl < ICC; ++icl) {
            float in[4][10];
            #pragma unroll
            for (int kh = 0; kh < 4; ++kh)
                #pragma unroll
                for (int c = 0; c < 10; ++c)
                    in[kh][c] = sx[icl][2 * ohl + kh][2 * ow0 + c];
            #pragma unroll
            for (int ol = 0; ol < 4; ++ol) {
                const int oc = ocg * 4 + ol;
                #pragma unroll
                for (int kh = 0; kh < 4; ++kh)
                    #pragma unroll
                    for (int kw = 0; kw < 4; ++kw) {
                        const float wv = sw[oc][icl * 16 + kh * 4 + kw];
                        #pragma unroll
                        for (int j = 0; j < 4; ++j)
                            acc[ol][j] = __fmaf_rn(in[kh][2 * j + kw], wv,
                                                   acc[ol][j]);
                    }
            }
        }
        __syncthreads();
    }
    #pragma unroll
    for (int ol = 0; ol < 4; ++ol) {
        const int oc = ocg * 4 + ol;
        const float bv = bias[oc];
        float r0 = __fadd_rn(acc[ol][0], bv), r1 = __fadd_rn(acc[ol][1], bv);
        float r2 = __fadd_rn(acc[ol][2], bv), r3 = __fadd_rn(acc[ol][3], bv);
        if (RELU) {
            r0 = fmaxf(r0, 0.f); r1 = fmaxf(r1, 0.f);
            r2 = fmaxf(r2, 0.f); r3 = fmaxf(r3, 0.f);
        }
        float4* o = reinterpret_cast<float4*>(
            &y[((size_t)(n * COUT + oc) * HOUT + oh) * WOUT + ow0]);
        *o = make_float4(r0, r1, r2, r3);
    }
}

// ---------------- deconv v2: k=4, s=2, p=1, op=0, fp32 ----------------------
// Thread computes 4 co x 8 ow; TOH=4 rows per block (2 oh-pairs).
// oh = 2*ih - 1 + kh; kh in {p1, p1+2}, p1=(oh+1)&1, row r1 holds kh=p1.
template<int CIN, int COUT, int HIN, int ICC, bool RELU>
__global__ void __launch_bounds__(256)
deconv_s2_v2(const float* __restrict__ x, const float* __restrict__ w,
             const float* __restrict__ bias, float* __restrict__ y)
{
    constexpr int WIN = HIN, HOUT = 2 * HIN, WOUT = 2 * WIN;
    constexpr int NOW8 = WOUT / 8, NOC4 = COUT / 4;
    static_assert(NOW8 * NOC4 * 4 == 256, "block mismatch");
    static_assert(CIN % ICC == 0, "chunking mismatch");
    constexpr int NCH = CIN / ICC;
    constexpr int LW  = (WIN + 2 + 3) & ~3;   // pad rows to 16B multiple
    constexpr int SWP = 20;                    // 16B-aligned f4, off-bank co

    __shared__ float sx[ICC][4][LW];
    __shared__ float sw[ICC][COUT][SWP];

    const int n   = blockIdx.x;
    const int oh0 = blockIdx.y * 4;
    const int t   = threadIdx.x;
    const int owg = t % NOW8;
    const int ocg = (t / NOW8) % NOC4;
    const int oq  = t / (NOW8 * NOC4);        // wave-uniform
    const int oh  = oh0 + oq;
    const int ihb = oh0 / 2 - 1;
    const int p1  = (oh + 1) & 1;
    const int r1  = ((oh + 1) >> 1) - ihb;    // 1..3; rows used: r1-1, r1

    float acc[4][8];
    #pragma unroll
    for (int i = 0; i < 4; ++i)
        #pragma unroll
        for (int j = 0; j < 8; ++j) acc[i][j] = 0.f;

    for (int ch = 0; ch < NCH; ++ch) {
        const int ic0 = ch * ICC;
        // stage weights as float4 (w: [ci][co][16] -> sw[icl][co][k])
        for (int idx = t; idx < ICC * COUT * 4; idx += 256) {
            const int k4  = idx & 3;
            const int co  = (idx >> 2) % COUT;
            const int icl = idx / (4 * COUT);
            const float4 v = reinterpret_cast<const float4*>(w)
                                [((size_t)(ic0 + icl) * COUT + co) * 4 + k4];
            *reinterpret_cast<float4*>(&sw[icl][co][k4 * 4]) = v;
        }
        // stage input rows ihb..ihb+3, col c -> iw = c-1 (zero-padded)
        for (int idx = t; idx < ICC * 4 * LW; idx += 256) {
            const int c   = idx % LW;
            const int r   = (idx / LW) & 3;
            const int icl = idx / (LW * 4);
            const int ih  = ihb + r;
            const int iw  = c - 1;
            float v = 0.f;
            if (ih >= 0 && ih < HIN && iw >= 0 && iw < WIN)
                v = x[((size_t)(n * CIN + ic0 + icl) * HIN + ih) * WIN + iw];
            sx[icl][r][c] = v;
        }
        __syncthreads();
        #pragma unroll
        for (int icl = 0; icl < ICC; ++icl) {
            // xv1 = row r1 (kh=p1), xv0 = row r1-1 (kh=p1+2); cols owg*4..+5
            float xv0[6], xv1[6];
            {
                const float4 a = *reinterpret_cast<const float4*>(&sx[icl][r1 - 1][owg * 4]);
                const float2 b = *reinterpret_cast<const float2*>(&sx[icl][r1 - 1][owg * 4 + 4]);
                xv0[0] = a.x; xv0[1] = a.y; xv0[2] = a.z; xv0[3] = a.w;
                xv0[4] = b.x; xv0[5] = b.y;
                const float4 c4 = *reinterpret_cast<const float4*>(&sx[icl][r1][owg * 4]);
                const float2 d  = *reinterpret_cast<const float2*>(&sx[icl][r1][owg * 4 + 4]);
                xv1[0] = c4.x; xv1[1] = c4.y; xv1[2] = c4.z; xv1[3] = c4.w;
                xv1[4] = d.x;  xv1[5] = d.y;
            }
            #pragma unroll
            for (int cl = 0; cl < 4; ++cl) {
                const int co = ocg * 4 + cl;
                const float4 w0 = *reinterpret_cast<const float4*>(&sw[icl][co][p1 * 4]);
                const float4 w1 = *reinterpret_cast<const float4*>(&sw[icl][co][(p1 + 2) * 4]);
                // j even: kw parity q1=1 -> .y/.w ; j odd: q1=0 -> .x/.z
                acc[cl][0] += xv1[1]*w0.y + xv0[1]*w1.y + xv1[0]*w0.w + xv0[0]*w1.w;
                acc[cl][1] += xv1[2]*w0.x + xv0[2]*w1.x + xv1[1]*w0.z + xv0[1]*w1.z;
                acc[cl][2] += xv1[2]*w0.y + xv0[2]*w1.y + xv1[1]*w0.w + xv0[1]*w1.w;
                acc[cl][3] += xv1[3]*w0.x + xv0[3]*w1.x + xv1[2]*w0.z + xv0[2]*w1.z;
                acc[cl][4] += xv1[3]*w0.y + xv0[3]*w1.y + xv1[2]*w0.w + xv0[2]*w1.w;
                acc[cl][5] += xv1[4]*w0.x + xv0[4]*w1.x + xv1[3]*w0.z + xv0[3]*w1.z;
                acc[cl][6] += xv1[4]*w0.y + xv0[4]*w1.y + xv1[3]*w0.w + xv0[3]*w1.w;
                acc[cl][7] += xv1[5]*w0.x + xv0[5]*w1.x + xv1[4]*w0.z + xv0[4]*w1.z;
            }
        }
        __syncthreads();
    }
    #pragma unroll
    for (int cl = 0; cl < 4; ++cl) {
        const int co = ocg * 4 + cl;
        const float bv = bias[co];
        float r[8];
        #pragma unroll
        for (int j = 0; j < 8; ++j) {
            r[j] = acc[cl][j] + bv;
            if (RELU) r[j] = fmaxf(r[j], 0.f);
        }
        float* o = &y[((size_t)(n * COUT + co) * HOUT + oh) * WOUT + owg * 8];
        *reinterpret_cast<float4*>(o)     = make_float4(r[0], r[1], r[2], r[3]);
        *reinterpret_cast<float4*>(o + 4) = make_float4(r[4], r[5], r[6], r[7]);
    }
}

// ---------------- deconv3: 32->3, 64->131, k=4 s2 p=0 op=1, sigmoid --------
__global__ void __launch_bounds__(256)
deconv3_sig(const float* __restrict__ x, const float* __restrict__ w,
            const float* __restrict__ bias, float* __restrict__ y)
{
    __shared__ float sx[32][2][64];
    __shared__ float sw[32][3][16];
    const int n = blockIdx.x;
    const int r = blockIdx.y;
    const int t = threadIdx.x;

    float* swf = &sw[0][0][0];
    for (int idx = t; idx < 32 * 3 * 16; idx += 256) swf[idx] = w[idx];
    for (int idx = t; idx < 32 * 2 * 64; idx += 256) {
        const int c  = idx & 63;
        const int rr = (idx >> 6) & 1;
        const int ci = idx >> 7;
        const int ih = r - 1 + rr;
        sx[ci][rr][c] = (ih >= 0 && ih < 64)
            ? x[((size_t)(n * 32 + ci) * 64 + ih) * 64 + c] : 0.f;
    }
    __syncthreads();
    const float b0 = bias[0], b1 = bias[1], b2 = bias[2];
    for (int p = t; p < 262; p += 256) {
        const int dh = p / 131;
        const int oh = 2 * r + dh;
        if (oh >= 131) continue;
        const int ow  = p - dh * 131;
        const int kh1 = oh & 1, kw1 = ow & 1;
        const int c1  = ow >> 1;
        const int c2  = c1 - 1;
        const bool v1 = (c1 < 64);
        const bool v2 = (c2 >= 0 && c2 < 64);
        float a0 = 0.f, a1 = 0.f, a2 = 0.f;
        const int w11 = kh1 * 4 + kw1;
        const int w21 = (kh1 + 2) * 4 + kw1;
        const int w12 = kh1 * 4 + kw1 + 2;
        const int w22 = (kh1 + 2) * 4 + kw1 + 2;
        #pragma unroll 8
        for (int ci = 0; ci < 32; ++ci) {
            const float x11 = v1 ? sx[ci][1][c1] : 0.f;
            const float x01 = v1 ? sx[ci][0][c1] : 0.f;
            const float x10 = v2 ? sx[ci][1][c2] : 0.f;
            const float x00 = v2 ? sx[ci][0][c2] : 0.f;
            a0 = fmaf(x11, sw[ci][0][w11], a0); a0 = fmaf(x01, sw[ci][0][w21], a0);
            a0 = fmaf(x10, sw[ci][0][w12], a0); a0 = fmaf(x00, sw[ci][0][w22], a0);
            a1 = fmaf(x11, sw[ci][1][w11], a1); a1 = fmaf(x01, sw[ci][1][w21], a1);
            a1 = fmaf(x10, sw[ci][1][w12], a1); a1 = fmaf(x00, sw[ci][1][w22], a1);
            a2 = fmaf(x11, sw[ci][2][w11], a2); a2 = fmaf(x01, sw[ci][2][w21], a2);
            a2 = fmaf(x10, sw[ci][2][w12], a2); a2 = fmaf(x00, sw[ci][2][w22], a2);
        }
        const size_t base = (size_t)n * 3 * 17161 + (size_t)oh * 131 + ow;
        y[base]             = 1.0f / (1.0f + expf(-(a0 + b0)));
        y[base + 17161]     = 1.0f / (1.0f + expf(-(a1 + b1)));
        y[base + 2 * 17161] = 1.0f / (1.0f + expf(-(a2 + b2)));
    }
}

// ---------------- codebook ||e_j||^2, numpy pairwise fp32 (FROZEN) ---------
__global__ void __launch_bounds__(256)
esum_np_kernel(const float* __restrict__ cb, float* __restrict__ esum)
{
    const int j = blockIdx.x * 256 + threadIdx.x;
    if (j < 512) {
        const float* row = cb + j * 64;
        esum[j] = pairwise64_sq([&](int c) { return row[c]; });
    }
}

// ---------------- VQ: numpy-fp32-replicated argmin (FROZEN) ----------------
__global__ void __launch_bounds__(256)
vq_kernel_np(const float* __restrict__ z, const float* __restrict__ cb,
             const float* __restrict__ esum, float* __restrict__ zq,
             float* __restrict__ oidx, float* __restrict__ oloss)
{
    __shared__ float scb[64][64];
    __shared__ float red[128];
    const int t  = threadIdx.x;
    const int i  = blockIdx.x * 128 + (t >> 1);
    const int cs = (t & 1) * 32;
    const int n  = i >> 8;
    const int hw = i & 255;
    const float* zb = z + (size_t)n * 16384 + hw;

    float zr[64];
    #pragma unroll
    for (int c = 0; c < 64; ++c) zr[c] = zb[(size_t)c * 256];

    const float zz = pairwise64_sq([&](int c) { return zr[c]; });

    float best = 3.4e38f;
    int bi = 0;
    float* scf = &scb[0][0];
    for (int ch = 0; ch < 8; ++ch) {
        __syncthreads();
        for (int idx2 = t; idx2 < 4096; idx2 += 256)
            scf[idx2] = cb[ch * 4096 + idx2];
        __syncthreads();
        #pragma unroll 1
        for (int j4 = 0; j4 < 32; j4 += 4) {
            const float4* p0 = reinterpret_cast<const float4*>(&scb[cs + j4 + 0][0]);
            const float4* p1 = reinterpret_cast<const float4*>(&scb[cs + j4 + 1][0]);
            const float4* p2 = reinterpret_cast<const float4*>(&scb[cs + j4 + 2][0]);
            const float4* p3 = reinterpret_cast<const float4*>(&scb[cs + j4 + 3][0]);
            float a0 = 0.f, a1 = 0.f, a2 = 0.f, a3 = 0.f;
            #pragma unroll
            for (int c4 = 0; c4 < 16; ++c4) {
                const float4 v0 = p0[c4];
                const float4 v1 = p1[c4];
                const float4 v2 = p2[c4];
                const float4 v3 = p3[c4];
                const int c = c4 * 4;
                a0 = __fmaf_rn(zr[c+0], v0.x, a0);
                a0 = __fmaf_rn(zr[c+1], v0.y, a0);
                a0 = __fmaf_rn(zr[c+2], v0.z, a0);
                a0 = __fmaf_rn(zr[c+3], v0.w, a0);
                a1 = __fmaf_rn(zr[c+0], v1.x, a1);
                a1 = __fmaf_rn(zr[c+1], v1.y, a1);
                a1 = __fmaf_rn(zr[c+2], v1.z, a1);
                a1 = __fmaf_rn(zr[c+3], v1.w, a1);
                a2 = __fmaf_rn(zr[c+0], v2.x, a2);
                a2 = __fmaf_rn(zr[c+1], v2.y, a2);
                a2 = __fmaf_rn(zr[c+2], v2.z, a2);
                a2 = __fmaf_rn(zr[c+3], v2.w, a2);
                a3 = __fmaf_rn(zr[c+0], v3.x, a3);
                a3 = __fmaf_rn(zr[c+1], v3.y, a3);
                a3 = __fmaf_rn(zr[c+2], v3.z, a3);
                a3 = __fmaf_rn(zr[c+3], v3.w, a3);
            }
            const int base = ch * 64 + cs + j4;
            const float d0 = __fsub_rn(__fadd_rn(zz, esum[base + 0]),
                                       __fmul_rn(2.0f, a0));
            const float d1 = __fsub_rn(__fadd_rn(zz, esum[base + 1]),
                                       __fmul_rn(2.0f, a1));
            const float d2 = __fsub_rn(__fadd_rn(zz, esum[base + 2]),
                                       __fmul_rn(2.0f, a2));
            const float d3 = __fsub_rn(__fadd_rn(zz, esum[base + 3]),
                                       __fmul_rn(2.0f, a3));
            if (d0 < best) { best = d0; bi = base + 0; }
            if (d1 < best) { best = d1; bi = base + 1; }
            if (d2 < best) { best = d2; bi = base + 2; }
            if (d3 < best) { best = d3; bi = base + 3; }
        }
    }
    {
        const float ob  = __shfl_xor(best, 1);
        const int   obi = __shfl_xor(bi, 1);
        if (ob < best || (ob == best && obi < bi)) { best = ob; bi = obi; }
    }
    if ((t & 1) == 0) {
        const float* e = cb + (size_t)bi * 64;
        float rs = 0.f;
        #pragma unroll
        for (int c = 0; c < 64; ++c) {
            const float qv = e[c];
            const float df = qv - zr[c];
            rs = fmaf(df, df, rs);
            zq[((size_t)n * 64 + c) * 256 + hw] = zr[c] + (qv - zr[c]);
        }
        oidx[i] = (float)bi;
        red[t >> 1] = rs;
    }
    __syncthreads();
    for (int s = 64; s > 0; s >>= 1) {
        if (t < s) red[t] += red[t + s];
        __syncthreads();
    }
    if (t == 0)
        atomicAdd(oloss, red[0] * (1.25f / (32768.0f * 64.0f)));
}

// ============================================================================
extern "C" void kernel_launch(void* const* d_in, const int* in_sizes, int n_in,
                              void* d_out, int out_size, void* d_ws, size_t ws_size,
                              hipStream_t stream)
{
    (void)in_sizes; (void)n_in; (void)out_size; (void)ws_size;
    const float* x   = (const float*)d_in[0];
    const float* ew1 = (const float*)d_in[1];
    const float* eb1 = (const float*)d_in[2];
    const float* ew2 = (const float*)d_in[3];
    const float* eb2 = (const float*)d_in[4];
    const float* ew3 = (const float*)d_in[5];
    const float* eb3 = (const float*)d_in[6];
    const float* cb  = (const float*)d_in[7];
    const float* dw1 = (const float*)d_in[8];
    const float* db1 = (const float*)d_in[9];
    const float* dw2 = (const float*)d_in[10];
    const float* db2 = (const float*)d_in[11];
    const float* dw3 = (const float*)d_in[12];
    const float* db3 = (const float*)d_in[13];
    float* out = (float*)d_out;
    float* ws  = (float*)d_ws;

    float* h1 = ws;                  // 128*32*64*64 = 16,777,216
    float* h2 = h1 + 16777216;       // 128*64*32*32 =  8,388,608
    float* z  = h2 + 8388608;        // 128*64*16*16 =  2,097,152
    float* zq = z  + 2097152;        //                 2,097,152
    float* es = zq + 2097152;        //                       512
    float* d1 = h2;                  // reuse: h2 dead after conv3
    float* d2 = h1;                  // reuse: h1 dead after conv2

    constexpr size_t RECON = (size_t)128 * 3 * 131 * 131;  // 6,589,824

    conv_s2<3, 32, 128, 2, 3, true ><<<dim3(128, 32), 256, 0, stream>>>(x,  ew1, eb1, h1);
    conv_s2<32, 64,  64, 2, 8, true ><<<dim3(128, 16), 256, 0, stream>>>(h1, ew2, eb2, h2);
    conv_s2<64, 64,  32, 4, 8, false><<<dim3(128,  4), 256, 0, stream>>>(h2, ew3, eb3, z);

    esum_np_kernel<<<dim3(2), 256, 0, stream>>>(cb, es);
    hipMemsetAsync(out + RECON, 0, sizeof(float), stream);   // vq_loss slot
    vq_kernel_np<<<dim3(256), 256, 0, stream>>>(z, cb, es, zq,
                                                out + RECON + 1, out + RECON);

    deconv_s2_v2<64, 64, 16,  8, true><<<dim3(128,  8), 256, 0, stream>>>(zq, dw1, db1, d1);
    deconv_s2_v2<64, 32, 32, 16, true><<<dim3(128, 16), 256, 0, stream>>>(d1, dw2, db2, d2);
    deconv3_sig<<<dim3(128, 66), 256, 0, stream>>>(d2, dw3, db3, out);
}

// Round 12
// 1145.580 us; speedup vs baseline: 1.2683x; 1.2683x over previous
//
#include <hip/hip_runtime.h>

// ============================================================================
// VQ-VAE forward, fp32, NCHW — numpy-fp32 bit-replication (PASSED R10).
//   FROZEN (bit-exact vs ref=np, do not reorder arithmetic):
//     - encoder convs: sequential __fmaf_rn in (ci,kh,kw) order
//     - zz/ee: numpy pairwise-8 reduction; d = (zz+ee) - 2*dot, strict-<
//   R12: revert R11's spilled v2 deconv (VGPR 256, 708MB scratch writes).
//        R10 deconv body + ONE change: thread map owg|ocg|ohl so ohl (and
//        thus p1/r1) is wave-uniform -> sw reads broadcast, conflicts drop.
// d_out layout (floats): [x_recon 128*3*131*131][vq_loss][idx 32768]
// ============================================================================

// numpy pairwise reduction for n=64 contiguous squares
template<typename F>
__device__ __forceinline__ float pairwise64_sq(F get)
{
    float r[8];
    #pragma unroll
    for (int j = 0; j < 8; ++j) {
        const float v = get(j);
        r[j] = __fmul_rn(v, v);
    }
    #pragma unroll
    for (int b = 1; b < 8; ++b)
        #pragma unroll
        for (int j = 0; j < 8; ++j) {
            const float v = get(8 * b + j);
            r[j] = __fadd_rn(r[j], __fmul_rn(v, v));
        }
    return __fadd_rn(__fadd_rn(__fadd_rn(r[0], r[1]), __fadd_rn(r[2], r[3])),
                     __fadd_rn(__fadd_rn(r[4], r[5]), __fadd_rn(r[6], r[7])));
}

// ---------------- encoder conv (FROZEN arithmetic) ----------------
template<int CIN, int COUT, int HIN, int TOH, int ICC, bool RELU>
__global__ void __launch_bounds__(256)
conv_s2(const float* __restrict__ x, const float* __restrict__ w,
        const float* __restrict__ bias, float* __restrict__ y)
{
    constexpr int WIN = HIN, HOUT = HIN / 2, WOUT = WIN / 2;
    constexpr int NOWG = WOUT / 4, NOCG = COUT / 4;
    static_assert(TOH * NOWG * NOCG == 256, "block mismatch");
    static_assert(CIN % ICC == 0, "chunking mismatch");
    constexpr int NCH = CIN / ICC;
    constexpr int NIR = 2 * TOH + 2;
    constexpr int LW  = WIN + 2;
    constexpr int SWP = ICC * 16 + 1;

    __shared__ float sx[ICC][NIR][LW];
    __shared__ float sw[COUT][SWP];

    const int n   = blockIdx.x;
    const int oh0 = blockIdx.y * TOH;
    const int t   = threadIdx.x;
    const int owg = t % NOWG;
    const int ohl = (t / NOWG) % TOH;
    const int ocg = t / (NOWG * TOH);
    const int oh  = oh0 + ohl;
    const int ow0 = owg * 4;
    const int ih0 = 2 * oh0 - 1;

    float acc[4][4];
    #pragma unroll
    for (int i = 0; i < 4; ++i)
        #pragma unroll
        for (int j = 0; j < 4; ++j) acc[i][j] = 0.f;

    for (int ch = 0; ch < NCH; ++ch) {
        const int ic0 = ch * ICC;
        for (int idx = t; idx < COUT * ICC * 16; idx += 256) {
            const int k   = idx & 15;
            const int icl = (idx >> 4) % ICC;
            const int oc  = idx / (16 * ICC);
            sw[oc][icl * 16 + k] = w[(oc * CIN + ic0 + icl) * 16 + k];
        }
        for (int idx = t; idx < ICC * NIR * LW; idx += 256) {
            const int c   = idx % LW;
            const int r   = (idx / LW) % NIR;
            const int icl = idx / (LW * NIR);
            const int ih  = ih0 + r;
            const int iw  = c - 1;
            float v = 0.f;
            if (ih >= 0 && ih < HIN && iw >= 0 && iw < WIN)
                v = x[((size_t)(n * CIN + ic0 + icl) * HIN + ih) * WIN + iw];
            sx[icl][r][c] = v;
        }
        __syncthreads();
        #pragma unroll
        for (int icl = 0; icl < ICC; ++icl) {
            float in[4][10];
            #pragma unroll
            for (int kh = 0; kh < 4; ++kh)
                #pragma unroll
                for (int c = 0; c < 10; ++c)
                    in[kh][c] = sx[icl][2 * ohl + kh][2 * ow0 + c];
            #pragma unroll
            for (int ol = 0; ol < 4; ++ol) {
                const int oc = ocg * 4 + ol;
                #pragma unroll
                for (int kh = 0; kh < 4; ++kh)
                    #pragma unroll
                    for (int kw = 0; kw < 4; ++kw) {
                        const float wv = sw[oc][icl * 16 + kh * 4 + kw];
                        #pragma unroll
                        for (int j = 0; j < 4; ++j)
                            acc[ol][j] = __fmaf_rn(in[kh][2 * j + kw], wv,
                                                   acc[ol][j]);
                    }
            }
        }
        __syncthreads();
    }
    #pragma unroll
    for (int ol = 0; ol < 4; ++ol) {
        const int oc = ocg * 4 + ol;
        const float bv = bias[oc];
        float r0 = __fadd_rn(acc[ol][0], bv), r1 = __fadd_rn(acc[ol][1], bv);
        float r2 = __fadd_rn(acc[ol][2], bv), r3 = __fadd_rn(acc[ol][3], bv);
        if (RELU) {
            r0 = fmaxf(r0, 0.f); r1 = fmaxf(r1, 0.f);
            r2 = fmaxf(r2, 0.f); r3 = fmaxf(r3, 0.f);
        }
        float4* o = reinterpret_cast<float4*>(
            &y[((size_t)(n * COUT + oc) * HOUT + oh) * WOUT + ow0]);
        *o = make_float4(r0, r1, r2, r3);
    }
}

// ---------------- deconv (ConvTranspose2d): k=4, s=2, p=1, op=0 -------------
// R10 body; thread map owg|ocg|ohl => ohl, p1, r1 wave-uniform.
template<int CIN, int COUT, int HIN, int TOH, int ICC, bool RELU>
__global__ void __launch_bounds__(256)
deconv_s2(const float* __restrict__ x, const float* __restrict__ w,
          const float* __restrict__ bias, float* __restrict__ y)
{
    constexpr int WIN = HIN, HOUT = 2 * HIN, WOUT = 2 * WIN;
    constexpr int NOWG = WOUT / 4, NOCG = COUT / 4;
    static_assert(TOH * NOWG * NOCG == 256, "block mismatch");
    static_assert(CIN % ICC == 0, "chunking mismatch");
    static_assert(TOH == 2, "row-tile fixed at 2");
    constexpr int NCH = CIN / ICC;
    constexpr int NIR = 3;
    constexpr int LW  = WIN + 2;

    __shared__ float sx[ICC][NIR][LW];
    __shared__ float sw[ICC][COUT][17];

    const int n   = blockIdx.x;
    const int oh0 = blockIdx.y * TOH;
    const int t   = threadIdx.x;
    const int owg = t % NOWG;                  // low bits: coalesced writes
    const int ocg = (t / NOWG) % NOCG;         // mid
    const int ohl = t / (NOWG * NOCG);         // top bit: wave-uniform
    const int oh  = oh0 + ohl;
    const int ow0 = owg * 4;
    const int ih0 = oh0 / 2 - 1;
    const int p1  = (oh + 1) & 1;              // wave-uniform now
    const int r1  = ((oh + 1) >> 1) - ih0;     // wave-uniform now

    float acc[4][4];
    #pragma unroll
    for (int i = 0; i < 4; ++i)
        #pragma unroll
        for (int j = 0; j < 4; ++j) acc[i][j] = 0.f;

    for (int ch = 0; ch < NCH; ++ch) {
        const int ic0 = ch * ICC;
        for (int idx = t; idx < ICC * COUT * 16; idx += 256) {
            const int k   = idx & 15;
            const int co  = (idx >> 4) % COUT;
            const int icl = idx / (16 * COUT);
            sw[icl][co][k] = w[((size_t)(ic0 + icl) * COUT + co) * 16 + k];
        }
        for (int idx = t; idx < ICC * NIR * LW; idx += 256) {
            const int c   = idx % LW;
            const int r   = (idx / LW) % NIR;
            const int icl = idx / (LW * NIR);
            const int ih  = ih0 + r;
            const int iw  = c - 1;
            float v = 0.f;
            if (ih >= 0 && ih < HIN && iw >= 0 && iw < WIN)
                v = x[((size_t)(n * CIN + ic0 + icl) * HIN + ih) * WIN + iw];
            sx[icl][r][c] = v;
        }
        __syncthreads();
        #pragma unroll
        for (int icl = 0; icl < ICC; ++icl) {
            float xv[2][4];
            #pragma unroll
            for (int rr = 0; rr < 2; ++rr)
                #pragma unroll
                for (int c = 0; c < 4; ++c)
                    xv[rr][c] = sx[icl][r1 - 1 + rr][ow0 / 2 + c];
            #pragma unroll
            for (int ol = 0; ol < 4; ++ol) {
                const int co = ocg * 4 + ol;
                float wv[2][4];
                #pragma unroll
                for (int a = 0; a < 2; ++a)
                    #pragma unroll
                    for (int kw = 0; kw < 4; ++kw)
                        wv[a][kw] = sw[icl][co][(p1 + 2 * a) * 4 + kw];
                acc[ol][0] += xv[1][1]*wv[0][1] + xv[0][1]*wv[1][1]
                            + xv[1][0]*wv[0][3] + xv[0][0]*wv[1][3];
                acc[ol][1] += xv[1][2]*wv[0][0] + xv[0][2]*wv[1][0]
                            + xv[1][1]*wv[0][2] + xv[0][1]*wv[1][2];
                acc[ol][2] += xv[1][2]*wv[0][1] + xv[0][2]*wv[1][1]
                            + xv[1][1]*wv[0][3] + xv[0][1]*wv[1][3];
                acc[ol][3] += xv[1][3]*wv[0][0] + xv[0][3]*wv[1][0]
                            + xv[1][2]*wv[0][2] + xv[0][2]*wv[1][2];
            }
        }
        __syncthreads();
    }
    #pragma unroll
    for (int ol = 0; ol < 4; ++ol) {
        const int co = ocg * 4 + ol;
        const float bv = bias[co];
        float r0 = acc[ol][0] + bv, r1 = acc[ol][1] + bv;
        float r2 = acc[ol][2] + bv, r3 = acc[ol][3] + bv;
        if (RELU) {
            r0 = fmaxf(r0, 0.f); r1 = fmaxf(r1, 0.f);
            r2 = fmaxf(r2, 0.f); r3 = fmaxf(r3, 0.f);
        }
        float4* o = reinterpret_cast<float4*>(
            &y[((size_t)(n * COUT + co) * HOUT + oh) * WOUT + ow0]);
        *o = make_float4(r0, r1, r2, r3);
    }
}

// ---------------- deconv3: 32->3, 64->131, k=4 s2 p=0 op=1, sigmoid --------
__global__ void __launch_bounds__(256)
deconv3_sig(const float* __restrict__ x, const float* __restrict__ w,
            const float* __restrict__ bias, float* __restrict__ y)
{
    __shared__ float sx[32][2][64];
    __shared__ float sw[32][3][16];
    const int n = blockIdx.x;
    const int r = blockIdx.y;
    const int t = threadIdx.x;

    float* swf = &sw[0][0][0];
    for (int idx = t; idx < 32 * 3 * 16; idx += 256) swf[idx] = w[idx];
    for (int idx = t; idx < 32 * 2 * 64; idx += 256) {
        const int c  = idx & 63;
        const int rr = (idx >> 6) & 1;
        const int ci = idx >> 7;
        const int ih = r - 1 + rr;
        sx[ci][rr][c] = (ih >= 0 && ih < 64)
            ? x[((size_t)(n * 32 + ci) * 64 + ih) * 64 + c] : 0.f;
    }
    __syncthreads();
    const float b0 = bias[0], b1 = bias[1], b2 = bias[2];
    for (int p = t; p < 262; p += 256) {
        const int dh = p / 131;
        const int oh = 2 * r + dh;
        if (oh >= 131) continue;
        const int ow  = p - dh * 131;
        const int kh1 = oh & 1, kw1 = ow & 1;
        const int c1  = ow >> 1;
        const int c2  = c1 - 1;
        const bool v1 = (c1 < 64);
        const bool v2 = (c2 >= 0 && c2 < 64);
        float a0 = 0.f, a1 = 0.f, a2 = 0.f;
        const int w11 = kh1 * 4 + kw1;
        const int w21 = (kh1 + 2) * 4 + kw1;
        const int w12 = kh1 * 4 + kw1 + 2;
        const int w22 = (kh1 + 2) * 4 + kw1 + 2;
        #pragma unroll 8
        for (int ci = 0; ci < 32; ++ci) {
            const float x11 = v1 ? sx[ci][1][c1] : 0.f;
            const float x01 = v1 ? sx[ci][0][c1] : 0.f;
            const float x10 = v2 ? sx[ci][1][c2] : 0.f;
            const float x00 = v2 ? sx[ci][0][c2] : 0.f;
            a0 = fmaf(x11, sw[ci][0][w11], a0); a0 = fmaf(x01, sw[ci][0][w21], a0);
            a0 = fmaf(x10, sw[ci][0][w12], a0); a0 = fmaf(x00, sw[ci][0][w22], a0);
            a1 = fmaf(x11, sw[ci][1][w11], a1); a1 = fmaf(x01, sw[ci][1][w21], a1);
            a1 = fmaf(x10, sw[ci][1][w12], a1); a1 = fmaf(x00, sw[ci][1][w22], a1);
            a2 = fmaf(x11, sw[ci][2][w11], a2); a2 = fmaf(x01, sw[ci][2][w21], a2);
            a2 = fmaf(x10, sw[ci][2][w12], a2); a2 = fmaf(x00, sw[ci][2][w22], a2);
        }
        const size_t base = (size_t)n * 3 * 17161 + (size_t)oh * 131 + ow;
        y[base]             = 1.0f / (1.0f + expf(-(a0 + b0)));
        y[base + 17161]     = 1.0f / (1.0f + expf(-(a1 + b1)));
        y[base + 2 * 17161] = 1.0f / (1.0f + expf(-(a2 + b2)));
    }
}

// ---------------- codebook ||e_j||^2, numpy pairwise fp32 (FROZEN) ---------
__global__ void __launch_bounds__(256)
esum_np_kernel(const float* __restrict__ cb, float* __restrict__ esum)
{
    const int j = blockIdx.x * 256 + threadIdx.x;
    if (j < 512) {
        const float* row = cb + j * 64;
        esum[j] = pairwise64_sq([&](int c) { return row[c]; });
    }
}

// ---------------- VQ: numpy-fp32-replicated argmin (FROZEN) ----------------
__global__ void __launch_bounds__(256)
vq_kernel_np(const float* __restrict__ z, const float* __restrict__ cb,
             const float* __restrict__ esum, float* __restrict__ zq,
             float* __restrict__ oidx, float* __restrict__ oloss)
{
    __shared__ float scb[64][64];
    __shared__ float red[128];
    const int t  = threadIdx.x;
    const int i  = blockIdx.x * 128 + (t >> 1);
    const int cs = (t & 1) * 32;
    const int n  = i >> 8;
    const int hw = i & 255;
    const float* zb = z + (size_t)n * 16384 + hw;

    float zr[64];
    #pragma unroll
    for (int c = 0; c < 64; ++c) zr[c] = zb[(size_t)c * 256];

    const float zz = pairwise64_sq([&](int c) { return zr[c]; });

    float best = 3.4e38f;
    int bi = 0;
    float* scf = &scb[0][0];
    for (int ch = 0; ch < 8; ++ch) {
        __syncthreads();
        for (int idx2 = t; idx2 < 4096; idx2 += 256)
            scf[idx2] = cb[ch * 4096 + idx2];
        __syncthreads();
        #pragma unroll 1
        for (int j4 = 0; j4 < 32; j4 += 4) {
            const float4* p0 = reinterpret_cast<const float4*>(&scb[cs + j4 + 0][0]);
            const float4* p1 = reinterpret_cast<const float4*>(&scb[cs + j4 + 1][0]);
            const float4* p2 = reinterpret_cast<const float4*>(&scb[cs + j4 + 2][0]);
            const float4* p3 = reinterpret_cast<const float4*>(&scb[cs + j4 + 3][0]);
            float a0 = 0.f, a1 = 0.f, a2 = 0.f, a3 = 0.f;
            #pragma unroll
            for (int c4 = 0; c4 < 16; ++c4) {
                const float4 v0 = p0[c4];
                const float4 v1 = p1[c4];
                const float4 v2 = p2[c4];
                const float4 v3 = p3[c4];
                const int c = c4 * 4;
                a0 = __fmaf_rn(zr[c+0], v0.x, a0);
                a0 = __fmaf_rn(zr[c+1], v0.y, a0);
                a0 = __fmaf_rn(zr[c+2], v0.z, a0);
                a0 = __fmaf_rn(zr[c+3], v0.w, a0);
                a1 = __fmaf_rn(zr[c+0], v1.x, a1);
                a1 = __fmaf_rn(zr[c+1], v1.y, a1);
                a1 = __fmaf_rn(zr[c+2], v1.z, a1);
                a1 = __fmaf_rn(zr[c+3], v1.w, a1);
                a2 = __fmaf_rn(zr[c+0], v2.x, a2);
                a2 = __fmaf_rn(zr[c+1], v2.y, a2);
                a2 = __fmaf_rn(zr[c+2], v2.z, a2);
                a2 = __fmaf_rn(zr[c+3], v2.w, a2);
                a3 = __fmaf_rn(zr[c+0], v3.x, a3);
                a3 = __fmaf_rn(zr[c+1], v3.y, a3);
                a3 = __fmaf_rn(zr[c+2], v3.z, a3);
                a3 = __fmaf_rn(zr[c+3], v3.w, a3);
            }
            const int base = ch * 64 + cs + j4;
            const float d0 = __fsub_rn(__fadd_rn(zz, esum[base + 0]),
                                       __fmul_rn(2.0f, a0));
            const float d1 = __fsub_rn(__fadd_rn(zz, esum[base + 1]),
                                       __fmul_rn(2.0f, a1));
            const float d2 = __fsub_rn(__fadd_rn(zz, esum[base + 2]),
                                       __fmul_rn(2.0f, a2));
            const float d3 = __fsub_rn(__fadd_rn(zz, esum[base + 3]),
                                       __fmul_rn(2.0f, a3));
            if (d0 < best) { best = d0; bi = base + 0; }
            if (d1 < best) { best = d1; bi = base + 1; }
            if (d2 < best) { best = d2; bi = base + 2; }
            if (d3 < best) { best = d3; bi = base + 3; }
        }
    }
    {
        const float ob  = __shfl_xor(best, 1);
        const int   obi = __shfl_xor(bi, 1);
        if (ob < best || (ob == best && obi < bi)) { best = ob; bi = obi; }
    }
    if ((t & 1) == 0) {
        const float* e = cb + (size_t)bi * 64;
        float rs = 0.f;
        #pragma unroll
        for (int c = 0; c < 64; ++c) {
            const float qv = e[c];
            const float df = qv - zr[c];
            rs = fmaf(df, df, rs);
            zq[((size_t)n * 64 + c) * 256 + hw] = zr[c] + (qv - zr[c]);
        }
        oidx[i] = (float)bi;
        red[t >> 1] = rs;
    }
    __syncthreads();
    for (int s = 64; s > 0; s >>= 1) {
        if (t < s) red[t] += red[t + s];
        __syncthreads();
    }
    if (t == 0)
        atomicAdd(oloss, red[0] * (1.25f / (32768.0f * 64.0f)));
}

// ============================================================================
extern "C" void kernel_launch(void* const* d_in, const int* in_sizes, int n_in,
                              void* d_out, int out_size, void* d_ws, size_t ws_size,
                              hipStream_t stream)
{
    (void)in_sizes; (void)n_in; (void)out_size; (void)ws_size;
    const float* x   = (const float*)d_in[0];
    const float* ew1 = (const float*)d_in[1];
    const float* eb1 = (const float*)d_in[2];
    const float* ew2 = (const float*)d_in[3];
    const float* eb2 = (const float*)d_in[4];
    const float* ew3 = (const float*)d_in[5];
    const float* eb3 = (const float*)d_in[6];
    const float* cb  = (const float*)d_in[7];
    const float* dw1 = (const float*)d_in[8];
    const float* db1 = (const float*)d_in[9];
    const float* dw2 = (const float*)d_in[10];
    const float* db2 = (const float*)d_in[11];
    const float* dw3 = (const float*)d_in[12];
    const float* db3 = (const float*)d_in[13];
    float* out = (float*)d_out;
    float* ws  = (float*)d_ws;

    float* h1 = ws;                  // 128*32*64*64 = 16,777,216
    float* h2 = h1 + 16777216;       // 128*64*32*32 =  8,388,608
    float* z  = h2 + 8388608;        // 128*64*16*16 =  2,097,152
    float* zq = z  + 2097152;        //                 2,097,152
    float* es = zq + 2097152;        //                       512
    float* d1 = h2;                  // reuse: h2 dead after conv3
    float* d2 = h1;                  // reuse: h1 dead after conv2

    constexpr size_t RECON = (size_t)128 * 3 * 131 * 131;  // 6,589,824

    conv_s2<3, 32, 128, 2, 3, true ><<<dim3(128, 32), 256, 0, stream>>>(x,  ew1, eb1, h1);
    conv_s2<32, 64,  64, 2, 8, true ><<<dim3(128, 16), 256, 0, stream>>>(h1, ew2, eb2, h2);
    conv_s2<64, 64,  32, 4, 8, false><<<dim3(128,  4), 256, 0, stream>>>(h2, ew3, eb3, z);

    esum_np_kernel<<<dim3(2), 256, 0, stream>>>(cb, es);
    hipMemsetAsync(out + RECON, 0, sizeof(float), stream);   // vq_loss slot
    vq_kernel_np<<<dim3(256), 256, 0, stream>>>(z, cb, es, zq,
                                                out + RECON + 1, out + RECON);

    deconv_s2<64, 64, 16, 2, 8, true><<<dim3(128, 16), 256, 0, stream>>>(zq, dw1, db1, d1);
    deconv_s2<64, 32, 32, 2, 8, true><<<dim3(128, 32), 256, 0, stream>>>(d1, dw2, db2, d2);
    deconv3_sig<<<dim3(128, 66), 256, 0, stream>>>(d2, dw3, db3, out);
}